// Round 10
// baseline (123.631 us; speedup 1.0000x reference)
//
#include <hip/hip_runtime.h>

#define BN 262144
#define S4 4
#define QS (BN / S4)     // 65536 samples per stripe
#define LNUM 15
// slab: 151 stages x 72 floats; stage lin = l*10 + net*5 + st; stage 150 = dup of stage 0
#define NSTG 151
#define NF4 (NSTG * 18)  // 2718 float4

extern "C" __global__ void build_slab(
    const float* __restrict__ Wi, const float* __restrict__ bi,
    const float* __restrict__ Wh, const float* __restrict__ bh,
    const float* __restrict__ Wo, const float* __restrict__ bo,
    float* __restrict__ slab) {
    int idx = blockIdx.x * 256 + threadIdx.x;
    if (idx >= NSTG * 72) return;
    int sl = idx / 72, k = idx % 72;
    if (sl == NSTG - 1) sl = 0;
    const int l = sl / 10, r = sl % 10, net = r / 5, st = r % 5;
    const int nb = l * 2 + net;
    float v;
    if (k < 64) {
        if (st == 0)      v = Wi[nb * 64 + k];
        else if (st < 4)  v = Wh[(nb * 3 + (st - 1)) * 64 + k];
        else              v = Wo[nb * 64 + k];
    } else {
        const int o = k - 64;
        if (st == 0)      v = bi[nb * 8 + o];
        else if (st < 4)  v = bh[(nb * 3 + (st - 1)) * 8 + o];
        else              v = bo[nb * 8 + o];
    }
    slab[idx] = v;
}

// access float k of an 18-float4 register buffer with compile-time k
#define WB(buf, k) ((k) % 4 == 0 ? buf[(k) / 4].x : (k) % 4 == 1 ? buf[(k) / 4].y \
                  : (k) % 4 == 2 ? buf[(k) / 4].z : buf[(k) / 4].w)

// stage sidx: 18 broadcast ds_read_b128 from LDS slab into a VGPR buffer
#define PREFL(dst, sidx)                                                     \
    {                                                                        \
        const float4* sp = &wls[(sidx) * 18];                                \
        _Pragma("unroll") for (int j = 0; j < 18; ++j) dst[j] = sp[j];       \
    }

// quad-sample matvec: 256 FMAs per stage, weights from VGPR stage buffer.
// LD = leading dim of the input array (16 for x, 8 for h/g).
template <int LD>
__device__ __forceinline__ void mv8x4(const float* __restrict__ in,
                                      const float4 buf[18], float out[4][8]) {
#pragma unroll
    for (int o = 0; o < 8; ++o) {
        const float w0 = WB(buf, o), bb = WB(buf, 64 + o);
#pragma unroll
        for (int s = 0; s < 4; ++s) out[s][o] = fmaf(in[s * LD], w0, bb);
    }
#pragma unroll
    for (int i = 1; i < 8; ++i)
#pragma unroll
        for (int o = 0; o < 8; ++o) {
            const float w = WB(buf, i * 8 + o);
#pragma unroll
            for (int s = 0; s < 4; ++s) out[s][o] = fmaf(in[s * LD + i], w, out[s][o]);
        }
}

__device__ __forceinline__ void lr8x4(float v[4][8]) {
#pragma unroll
    for (int s = 0; s < 4; ++s)
#pragma unroll
        for (int o = 0; o < 8; ++o) v[s][o] = fmaxf(v[s][o], 0.01f * v[s][o]);
}

// 1 thread = 4 samples; 1 block/CU; weights LDS-resident, broadcast into
// ping-pong VGPR buffers one stage ahead. 4x FMA per slab-read-wave vs r9
// halves the LDS-BW bottleneck; 512-VGPR budget keeps everything spill-free.
extern "C" __global__ void __launch_bounds__(256, 1) flow_fwd(
    const float* __restrict__ z, const float* __restrict__ slab,
    const int* __restrict__ perms,
    float* __restrict__ outy, float* __restrict__ outld) {
    __shared__ float4 wls[NF4];       // 43.5 KB weight slab
    __shared__ float xs[256 * 69];    // 4 stride-17 permute slots/thread (+1 pad)
    const int t = threadIdx.x;
    const int i0 = blockIdx.x * 256 + t;

    {   // block-cooperative slab copy (one-time)
        const float4* gs = reinterpret_cast<const float4*>(slab);
        for (int k = t; k < NF4; k += 256) wls[k] = gs[k];
    }

    float x[4][16];
#pragma unroll
    for (int s = 0; s < 4; ++s) {
        const float4* zp = reinterpret_cast<const float4*>(z + (long)(i0 + s * QS) * 16);
#pragma unroll
        for (int q = 0; q < 4; ++q) {
            float4 a = zp[q];
            x[s][4 * q] = a.x; x[s][4 * q + 1] = a.y;
            x[s][4 * q + 2] = a.z; x[s][4 * q + 3] = a.w;
        }
    }
    float ld[4] = {0.f, 0.f, 0.f, 0.f};
    __syncthreads();

    float4 A[18], Bq[18];
    PREFL(A, 0)

#pragma unroll 1
    for (int l = 0; l < LNUM; ++l) {
        const int base = l * 10;
        float h[4][8], g[4][8], sf[4][8], bf[4][8];
        // net 0 (log_s): stages base+0..4 ; net 1 (b): base+5..9
        PREFL(Bq, base + 1)  mv8x4<16>(&x[0][0], A, h);  lr8x4(h);
        PREFL(A,  base + 2)  mv8x4<8>(&h[0][0], Bq, g);  lr8x4(g);
        PREFL(Bq, base + 3)  mv8x4<8>(&g[0][0], A, h);   lr8x4(h);
        PREFL(A,  base + 4)  mv8x4<8>(&h[0][0], Bq, g);  lr8x4(g);
        PREFL(Bq, base + 5)  mv8x4<8>(&g[0][0], A, sf);
        PREFL(A,  base + 6)  mv8x4<16>(&x[0][0], Bq, h); lr8x4(h);
        PREFL(Bq, base + 7)  mv8x4<8>(&h[0][0], A, g);   lr8x4(g);
        PREFL(A,  base + 8)  mv8x4<8>(&g[0][0], Bq, h);  lr8x4(h);
        PREFL(Bq, base + 9)  mv8x4<8>(&h[0][0], A, g);   lr8x4(g);
        PREFL(A,  base + 10) mv8x4<8>(&g[0][0], Bq, bf); // also next layer stage 0

#pragma unroll
        for (int s = 0; s < 4; ++s)
#pragma unroll
            for (int k = 0; k < 8; ++k) {
                const float cs = fminf(fmaxf(sf[s][k], -5.f), 5.f);
                ld[s] += cs;
                x[s][8 + k] = fmaf(__expf(cs) + 1e-6f, x[s][8 + k], bf[s][k]);
            }
        // register permutation via private LDS slots (uniform runtime indices)
        float* __restrict__ ms = &xs[t * 69];
#pragma unroll
        for (int s = 0; s < 4; ++s)
#pragma unroll
            for (int p = 0; p < 16; ++p) ms[s * 17 + p] = x[s][p];
        const int* __restrict__ pl = perms + l * 16;
#pragma unroll
        for (int j = 0; j < 16; ++j) {
            const int pj = pl[j];
#pragma unroll
            for (int s = 0; s < 4; ++s) x[s][j] = ms[s * 17 + pj];
        }
    }

#pragma unroll
    for (int s = 0; s < 4; ++s) {
        float4* ya = reinterpret_cast<float4*>(outy + (long)(i0 + s * QS) * 16);
#pragma unroll
        for (int q = 0; q < 4; ++q) {
            float4 a;
            a.x = x[s][4 * q]; a.y = x[s][4 * q + 1];
            a.z = x[s][4 * q + 2]; a.w = x[s][4 * q + 3];
            ya[q] = a;
        }
        outld[i0 + s * QS] = ld[s];
    }
}

extern "C" void kernel_launch(void* const* d_in, const int* in_sizes, int n_in,
                              void* d_out, int out_size, void* d_ws, size_t ws_size,
                              hipStream_t stream) {
    const float* z = (const float*)d_in[0];
    const float* Wi = (const float*)d_in[1];
    const float* bi = (const float*)d_in[2];
    const float* Wh = (const float*)d_in[3];
    const float* bh = (const float*)d_in[4];
    const float* Wo = (const float*)d_in[5];
    const float* bo = (const float*)d_in[6];
    const int* perms = (const int*)d_in[7];
    float* out = (float*)d_out;
    float* slab = (float*)d_ws;   // 151*72 floats

    hipLaunchKernelGGL(build_slab, dim3((NSTG * 72 + 255) / 256), dim3(256), 0, stream,
                       Wi, bi, Wh, bh, Wo, bo, slab);
    hipLaunchKernelGGL(flow_fwd, dim3(QS / 256), dim3(256), 0, stream,
                       z, slab, perms, out, out + (size_t)BN * 16);
}

// Round 11
// 119.559 us; speedup vs baseline: 1.0341x; 1.0341x over previous
//
#include <hip/hip_runtime.h>

#define BN 262144
#define S4 4
#define QS (BN / S4)     // 65536 samples per stripe
#define LNUM 15
// slab: 151 stages x 72 floats, per stage: [bias 8][W 64 row-major]; stage 150 = dup of 0
#define NSTG 151
#define NF4 (NSTG * 18)  // float4 count; groups of 6 float4 (3 groups/stage)

extern "C" __global__ void build_slab(
    const float* __restrict__ Wi, const float* __restrict__ bi,
    const float* __restrict__ Wh, const float* __restrict__ bh,
    const float* __restrict__ Wo, const float* __restrict__ bo,
    float* __restrict__ slab) {
    int idx = blockIdx.x * 256 + threadIdx.x;
    if (idx >= NSTG * 72) return;
    int sl = idx / 72, k = idx % 72;
    if (sl == NSTG - 1) sl = 0;
    const int l = sl / 10, r = sl % 10, net = r / 5, st = r % 5;
    const int nb = l * 2 + net;
    float v;
    if (k < 8) {       // bias first
        if (st == 0)      v = bi[nb * 8 + k];
        else if (st < 4)  v = bh[(nb * 3 + (st - 1)) * 8 + k];
        else              v = bo[nb * 8 + k];
    } else {
        const int kk = k - 8;
        if (st == 0)      v = Wi[nb * 64 + kk];
        else if (st < 4)  v = Wh[(nb * 3 + (st - 1)) * 64 + kk];
        else              v = Wo[nb * 64 + kk];
    }
    slab[idx] = v;
}

// float k of a 6-float4 group buffer (compile-time k)
#define GB(gb, k) ((k) % 4 == 0 ? gb[(k) / 4].x : (k) % 4 == 1 ? gb[(k) / 4].y \
                 : (k) % 4 == 2 ? gb[(k) / 4].z : gb[(k) / 4].w)

// chunk A: consume bias + rows 0,1 from B0; refill B0 with group k+3; fence
#define CHA(IN, OUT)                                                          \
    {                                                                         \
        _Pragma("unroll") for (int o = 0; o < 8; ++o) {                       \
            const float bb = GB(B0, o);                                       \
            const float w0 = GB(B0, 8 + o), w1 = GB(B0, 16 + o);              \
            _Pragma("unroll") for (int s = 0; s < 4; ++s)                     \
                OUT[s][o] = fmaf(IN[s][1], w1, fmaf(IN[s][0], w0, bb));       \
        }                                                                     \
        _Pragma("unroll") for (int j = 0; j < 6; ++j) B0[j] = gptr[j];        \
        gptr += 6;                                                            \
        __builtin_amdgcn_sched_barrier(0);                                    \
    }
// chunk B: rows 2,3,4 from B1
#define CHB(IN, OUT)                                                          \
    {                                                                         \
        _Pragma("unroll") for (int o = 0; o < 8; ++o) {                       \
            const float w2 = GB(B1, o), w3 = GB(B1, 8 + o), w4 = GB(B1, 16 + o); \
            _Pragma("unroll") for (int s = 0; s < 4; ++s)                     \
                OUT[s][o] = fmaf(IN[s][4], w4,                                 \
                             fmaf(IN[s][3], w3, fmaf(IN[s][2], w2, OUT[s][o]))); \
        }                                                                     \
        _Pragma("unroll") for (int j = 0; j < 6; ++j) B1[j] = gptr[j];        \
        gptr += 6;                                                            \
        __builtin_amdgcn_sched_barrier(0);                                    \
    }
// chunk C: rows 5,6,7 from B2 (+ optional leaky-relu)
#define CHC(IN, OUT, DOLR)                                                    \
    {                                                                         \
        _Pragma("unroll") for (int o = 0; o < 8; ++o) {                       \
            const float w5 = GB(B2, o), w6 = GB(B2, 8 + o), w7 = GB(B2, 16 + o); \
            _Pragma("unroll") for (int s = 0; s < 4; ++s) {                   \
                float a = fmaf(IN[s][7], w7,                                   \
                            fmaf(IN[s][6], w6, fmaf(IN[s][5], w5, OUT[s][o]))); \
                OUT[s][o] = (DOLR) ? fmaxf(a, 0.01f * a) : a;                 \
            }                                                                 \
        }                                                                     \
        _Pragma("unroll") for (int j = 0; j < 6; ++j) B2[j] = gptr[j];        \
        gptr += 6;                                                            \
        __builtin_amdgcn_sched_barrier(0);                                    \
    }
#define STG(IN, OUT, DOLR) CHA(IN, OUT) CHB(IN, OUT) CHC(IN, OUT, DOLR)

// 1 thread = 4 samples; weights LDS-resident, streamed through 3 rotating
// 6-float4 VGPR group buffers, depth-2-group prefetch pinned by sched_barrier.
extern "C" __global__ void __launch_bounds__(256, 1) flow_fwd(
    const float* __restrict__ z, const float* __restrict__ slab,
    const int* __restrict__ perms,
    float* __restrict__ outy, float* __restrict__ outld) {
    __shared__ float4 wls[NF4];       // 43.5 KB weight slab
    __shared__ float xs[256 * 69];    // 4 stride-17 permute slots/thread (70.6 KB)
    __shared__ int pls[LNUM * 16];    // perms in LDS (keeps loop pure-DS domain)
    const int t = threadIdx.x;
    const int i0 = blockIdx.x * 256 + t;

    {   // one-time block-cooperative staging
        const float4* gs = reinterpret_cast<const float4*>(slab);
        for (int k = t; k < NF4; k += 256) wls[k] = gs[k];
        if (t < LNUM * 16) pls[t] = perms[t];
    }

    float x[4][16];
#pragma unroll
    for (int s = 0; s < 4; ++s) {
        const float4* zp = reinterpret_cast<const float4*>(z + (long)(i0 + s * QS) * 16);
#pragma unroll
        for (int q = 0; q < 4; ++q) {
            float4 a = zp[q];
            x[s][4 * q] = a.x; x[s][4 * q + 1] = a.y;
            x[s][4 * q + 2] = a.z; x[s][4 * q + 3] = a.w;
        }
    }
    float ld[4] = {0.f, 0.f, 0.f, 0.f};
    __syncthreads();

    float4 B0[6], B1[6], B2[6];
    const float4* gptr = wls;
    // prologue: fill the 3-group pipeline
#pragma unroll
    for (int j = 0; j < 6; ++j) B0[j] = gptr[j];
    gptr += 6;
#pragma unroll
    for (int j = 0; j < 6; ++j) B1[j] = gptr[j];
    gptr += 6;
#pragma unroll
    for (int j = 0; j < 6; ++j) B2[j] = gptr[j];
    gptr += 6;
    __builtin_amdgcn_sched_barrier(0);

#pragma unroll 1
    for (int l = 0; l < LNUM; ++l) {
        float h[4][8], g[4][8], sf[4][8], bf[4][8];
        // net 0: log_s
        STG(x, h, 1) STG(h, g, 1) STG(g, h, 1) STG(h, g, 1) STG(g, sf, 0)
        // net 1: b
        STG(x, h, 1) STG(h, g, 1) STG(g, h, 1) STG(h, g, 1) STG(g, bf, 0)

#pragma unroll
        for (int s = 0; s < 4; ++s)
#pragma unroll
            for (int k = 0; k < 8; ++k) {
                const float cs = fminf(fmaxf(sf[s][k], -5.f), 5.f);
                ld[s] += cs;
                x[s][8 + k] = fmaf(__expf(cs) + 1e-6f, x[s][8 + k], bf[s][k]);
            }
        // register permutation via private LDS slots (uniform runtime indices)
        float* __restrict__ ms = &xs[t * 69];
#pragma unroll
        for (int s = 0; s < 4; ++s)
#pragma unroll
            for (int p = 0; p < 16; ++p) ms[s * 17 + p] = x[s][p];
        const int* __restrict__ pl = pls + l * 16;
#pragma unroll
        for (int j = 0; j < 16; ++j) {
            const int pj = pl[j];
#pragma unroll
            for (int s = 0; s < 4; ++s) x[s][j] = ms[s * 17 + pj];
        }
    }

#pragma unroll
    for (int s = 0; s < 4; ++s) {
        float4* ya = reinterpret_cast<float4*>(outy + (long)(i0 + s * QS) * 16);
#pragma unroll
        for (int q = 0; q < 4; ++q) {
            float4 a;
            a.x = x[s][4 * q]; a.y = x[s][4 * q + 1];
            a.z = x[s][4 * q + 2]; a.w = x[s][4 * q + 3];
            ya[q] = a;
        }
        outld[i0 + s * QS] = ld[s];
    }
}

extern "C" void kernel_launch(void* const* d_in, const int* in_sizes, int n_in,
                              void* d_out, int out_size, void* d_ws, size_t ws_size,
                              hipStream_t stream) {
    const float* z = (const float*)d_in[0];
    const float* Wi = (const float*)d_in[1];
    const float* bi = (const float*)d_in[2];
    const float* Wh = (const float*)d_in[3];
    const float* bh = (const float*)d_in[4];
    const float* Wo = (const float*)d_in[5];
    const float* bo = (const float*)d_in[6];
    const int* perms = (const int*)d_in[7];
    float* out = (float*)d_out;
    float* slab = (float*)d_ws;   // 151*72 floats

    hipLaunchKernelGGL(build_slab, dim3((NSTG * 72 + 255) / 256), dim3(256), 0, stream,
                       Wi, bi, Wh, bh, Wo, bo, slab);
    hipLaunchKernelGGL(flow_fwd, dim3(QS / 256), dim3(256), 0, stream,
                       z, slab, perms, out, out + (size_t)BN * 16);
}

// Round 13
// 95.031 us; speedup vs baseline: 1.3010x; 1.2581x over previous
//
#include <hip/hip_runtime.h>

#define BN 262144
#define HALF (BN / 2)
#define LNUM 15
// slab: 151 stages x 72 floats, per stage: [bias 8][W 64 row-major]; stage 150 = dup of 0
#define NSTG 151
#define NF4 (NSTG * 18)
#define LOG2E 1.4426950408889634f
#define LN2 0.6931471805599453f
#define L2CLIP 7.2134752044448170f   // 5*log2e

extern "C" __global__ void build_slab(
    const float* __restrict__ Wi, const float* __restrict__ bi,
    const float* __restrict__ Wh, const float* __restrict__ bh,
    const float* __restrict__ Wo, const float* __restrict__ bo,
    float* __restrict__ slab) {
    int idx = blockIdx.x * 256 + threadIdx.x;
    if (idx >= NSTG * 72) return;
    int sl = idx / 72, k = idx % 72;
    if (sl == NSTG - 1) sl = 0;
    const int l = sl / 10, r = sl % 10, net = r / 5, st = r % 5;
    const int nb = l * 2 + net;
    // net0 stage4 produces log_s: pre-scale by log2e so kernel uses exp2
    const float sc = (net == 0 && st == 4) ? LOG2E : 1.0f;
    float v;
    if (k < 8) {
        if (st == 0)      v = bi[nb * 8 + k];
        else if (st < 4)  v = bh[(nb * 3 + (st - 1)) * 8 + k];
        else              v = bo[nb * 8 + k] * sc;
    } else {
        const int kk = k - 8;
        if (st == 0)      v = Wi[nb * 64 + kk];
        else if (st < 4)  v = Wh[(nb * 3 + (st - 1)) * 64 + kk];
        else              v = Wo[nb * 64 + kk] * sc;
    }
    slab[idx] = v;
}

// cumulative maps: logical x[j] at layer l lives at physical slot c[l][j]
extern "C" __global__ void compose_perms(const int* __restrict__ perms, int* __restrict__ c) {
    if (threadIdx.x != 0 || blockIdx.x != 0) return;
    int cur[16];
    for (int j = 0; j < 16; ++j) { cur[j] = j; c[j] = j; }
    for (int l = 0; l < LNUM; ++l) {
        int nx[16];
        for (int j = 0; j < 16; ++j) nx[j] = cur[perms[l * 16 + j]];
        for (int j = 0; j < 16; ++j) { c[(l + 1) * 16 + j] = nx[j]; cur[j] = nx[j]; }
    }
}

// float k of a 6-float4 group buffer (compile-time k)
#define GB(gb, k) ((k) % 4 == 0 ? gb[(k) / 4].x : (k) % 4 == 1 ? gb[(k) / 4].y \
                 : (k) % 4 == 2 ? gb[(k) / 4].z : gb[(k) / 4].w)

// chunk A: bias + rows 0,1 from BUF; refill BUF with group 3 ahead; fence
#define CHA(IN, OUT, BUF)                                                     \
    {                                                                         \
        _Pragma("unroll") for (int o = 0; o < 8; ++o) {                       \
            const float bb = GB(BUF, o);                                      \
            const float w0 = GB(BUF, 8 + o), w1 = GB(BUF, 16 + o);            \
            _Pragma("unroll") for (int s = 0; s < 2; ++s)                     \
                OUT[s][o] = fmaf(IN[s][1], w1, fmaf(IN[s][0], w0, bb));       \
        }                                                                     \
        _Pragma("unroll") for (int j = 0; j < 6; ++j) BUF[j] = gptr[j];       \
        gptr += 6;                                                            \
        __builtin_amdgcn_sched_barrier(0);                                    \
    }
#define CHB(IN, OUT, BUF)                                                     \
    {                                                                         \
        _Pragma("unroll") for (int o = 0; o < 8; ++o) {                       \
            const float w2 = GB(BUF, o), w3 = GB(BUF, 8 + o), w4 = GB(BUF, 16 + o); \
            _Pragma("unroll") for (int s = 0; s < 2; ++s)                     \
                OUT[s][o] = fmaf(IN[s][4], w4,                                 \
                             fmaf(IN[s][3], w3, fmaf(IN[s][2], w2, OUT[s][o]))); \
        }                                                                     \
        _Pragma("unroll") for (int j = 0; j < 6; ++j) BUF[j] = gptr[j];       \
        gptr += 6;                                                            \
        __builtin_amdgcn_sched_barrier(0);                                    \
    }
#define CHC(IN, OUT, BUF, DOLR)                                               \
    {                                                                         \
        _Pragma("unroll") for (int o = 0; o < 8; ++o) {                       \
            const float w5 = GB(BUF, o), w6 = GB(BUF, 8 + o), w7 = GB(BUF, 16 + o); \
            _Pragma("unroll") for (int s = 0; s < 2; ++s) {                   \
                float a = fmaf(IN[s][7], w7,                                   \
                            fmaf(IN[s][6], w6, fmaf(IN[s][5], w5, OUT[s][o]))); \
                OUT[s][o] = (DOLR) ? fmaxf(a, 0.01f * a) : a;                 \
            }                                                                 \
        }                                                                     \
        _Pragma("unroll") for (int j = 0; j < 6; ++j) BUF[j] = gptr[j];       \
        gptr += 6;                                                            \
        __builtin_amdgcn_sched_barrier(0);                                    \
    }
// one 8x8 stage = 3 chunks rotating through B0,B1,B2
#define STG(IN, OUT, DOLR) CHA(IN, OUT, B0) CHB(IN, OUT, B1) CHC(IN, OUT, B2, DOLR)

// S=2 samples/thread, 8 waves/CU. x LDS-resident (composed perms index it);
// weights stream LDS->3 rotating VGPR group buffers, pinned by sched_barrier.
extern "C" __global__ void __launch_bounds__(512) flow_fwd(
    const float* __restrict__ z, const float* __restrict__ slab,
    const int* __restrict__ cperm,
    float* __restrict__ outy, float* __restrict__ outld) {
    __shared__ float4 wls[NF4];       // 43.5 KB
    __shared__ float xs[512 * 33];    // 67.6 KB: per-thread {A:0..15, B:16..31, pad}
    const int t = threadIdx.x;
    const long i = (long)blockIdx.x * 512 + t;
    float* __restrict__ myx = &xs[t * 33];

    {   // one-time block-cooperative slab copy
        const float4* gs = reinterpret_cast<const float4*>(slab);
        for (int k = t; k < NF4; k += 512) wls[k] = gs[k];
    }
    {   // load z into the LDS-resident x slots
        const float4* zp = reinterpret_cast<const float4*>(z + i * 16);
        const float4* zq = reinterpret_cast<const float4*>(z + (i + HALF) * 16);
#pragma unroll
        for (int q = 0; q < 4; ++q) {
            float4 a = zp[q], b = zq[q];
            myx[4 * q] = a.x; myx[4 * q + 1] = a.y; myx[4 * q + 2] = a.z; myx[4 * q + 3] = a.w;
            myx[16 + 4 * q] = b.x; myx[17 + 4 * q] = b.y; myx[18 + 4 * q] = b.z; myx[19 + 4 * q] = b.w;
        }
    }
    float ld2A = 0.f, ld2B = 0.f;
    __syncthreads();

    float4 B0[6], B1[6], B2[6];
#pragma unroll
    for (int j = 0; j < 6; ++j) { B0[j] = wls[j]; B1[j] = wls[6 + j]; B2[j] = wls[12 + j]; }
    const float4* gptr = wls + 18;
    __builtin_amdgcn_sched_barrier(0);

#pragma unroll 1
    for (int l = 0; l < LNUM; ++l) {
        const int* __restrict__ cl = cperm + l * 16;   // block-uniform -> s_load
        float in2[2][8];
#pragma unroll
        for (int j = 0; j < 8; ++j) {   // gather z_l once, reused by both nets
            const int off = cl[j];
            in2[0][j] = myx[off];
            in2[1][j] = myx[16 + off];
        }
        float h[2][8], g[2][8], sf[2][8], bf[2][8];
        // net 0: log_s (log2 domain)
        STG(in2, h, 1) STG(h, g, 1) STG(g, h, 1) STG(h, g, 1) STG(g, sf, 0)
        // net 1: b
        STG(in2, h, 1) STG(h, g, 1) STG(g, h, 1) STG(h, g, 1) STG(g, bf, 0)

#pragma unroll
        for (int k = 0; k < 8; ++k) {
            const int off = cl[8 + k];
            const float cA = fminf(fmaxf(sf[0][k], -L2CLIP), L2CLIP);
            const float cB = fminf(fmaxf(sf[1][k], -L2CLIP), L2CLIP);
            ld2A += cA; ld2B += cB;
            myx[off]      = fmaf(__builtin_amdgcn_exp2f(cA) + 1e-6f, myx[off],      bf[0][k]);
            myx[16 + off] = fmaf(__builtin_amdgcn_exp2f(cB) + 1e-6f, myx[16 + off], bf[1][k]);
        }
    }

    {   // final gather through c[15] and store
        const int* __restrict__ cf = cperm + LNUM * 16;
        float4 oa[4], ob[4];
#pragma unroll
        for (int q = 0; q < 4; ++q) {
            const int c0 = cf[4 * q], c1 = cf[4 * q + 1], c2 = cf[4 * q + 2], c3 = cf[4 * q + 3];
            oa[q].x = myx[c0]; oa[q].y = myx[c1]; oa[q].z = myx[c2]; oa[q].w = myx[c3];
            ob[q].x = myx[16 + c0]; ob[q].y = myx[16 + c1];
            ob[q].z = myx[16 + c2]; ob[q].w = myx[16 + c3];
        }
        float4* ya = reinterpret_cast<float4*>(outy + i * 16);
        float4* yb = reinterpret_cast<float4*>(outy + (i + HALF) * 16);
#pragma unroll
        for (int q = 0; q < 4; ++q) { ya[q] = oa[q]; yb[q] = ob[q]; }
        outld[i] = ld2A * LN2;
        outld[i + HALF] = ld2B * LN2;
    }
}

extern "C" void kernel_launch(void* const* d_in, const int* in_sizes, int n_in,
                              void* d_out, int out_size, void* d_ws, size_t ws_size,
                              hipStream_t stream) {
    const float* z = (const float*)d_in[0];
    const float* Wi = (const float*)d_in[1];
    const float* bi = (const float*)d_in[2];
    const float* Wh = (const float*)d_in[3];
    const float* bh = (const float*)d_in[4];
    const float* Wo = (const float*)d_in[5];
    const float* bo = (const float*)d_in[6];
    const int* perms = (const int*)d_in[7];
    float* out = (float*)d_out;
    float* slab = (float*)d_ws;                    // NSTG*72 floats
    int* cperm = (int*)(slab + NSTG * 72);         // (LNUM+1)*16 ints

    hipLaunchKernelGGL(build_slab, dim3((NSTG * 72 + 255) / 256), dim3(256), 0, stream,
                       Wi, bi, Wh, bh, Wo, bo, slab);
    hipLaunchKernelGGL(compose_perms, dim3(1), dim3(64), 0, stream, perms, cperm);
    hipLaunchKernelGGL(flow_fwd, dim3(HALF / 512), dim3(512), 0, stream,
                       z, slab, cperm, out, out + (size_t)BN * 16);
}